// Round 13
// baseline (30.875 us; speedup 1.0000x reference)
//
#include <hip/hip_runtime.h>
#include <math.h>

typedef _Float16 h4    __attribute__((ext_vector_type(4)));
typedef _Float16 half8 __attribute__((ext_vector_type(8)));
typedef float    f32x4 __attribute__((ext_vector_type(4)));

constexpr int B = 4, C = 64, H = 96, W = 96;
constexpr int NQ = C / 4;                   // 16 channel-quads
constexpr int KT = 9, OFFC = 18;
constexpr int HW = H * W;
constexpr int PAD = 4;                      // zero halo
constexpr int HP = H + 2 * PAD, WP = W + 2 * PAD;   // 104 x 104
constexpr int HPWP = HP * WP;
constexpr int WDF_HALFS = 4 * KT * 2 * 64 * 8;   // 36864  [m][tap][ks][lane][j]
constexpr int WOF_HALFS = 2 * KT * 2 * 64 * 8;   // 18432  [mf][tap][ks][lane][j]

struct h4x2 { h4 a, b; };                   // 16B: two adjacent columns (x0, x0+1)

// ---------------------------------------------------------------------------
// Prep: quad-interleaved f16 zero-halo pad + MFMA A-frag weights
// (identical to rounds 10-12; layouts verified).
// ---------------------------------------------------------------------------
__global__ __launch_bounds__(256) void prep(
        const float* __restrict__ x, const float* __restrict__ w_off,
        const float* __restrict__ w_dc,
        h4* __restrict__ xpad4, _Float16* __restrict__ wdf,
        _Float16* __restrict__ wof) {
    const int i = blockIdx.x * 256 + threadIdx.x;   // covers B*NQ*HPWP exactly
    {
        int col = i % WP; int t = i / WP; int row = t % HP; int bq = t / HP;
        int b = bq / NQ, q = bq % NQ;
        int h = row - PAD, w = col - PAD;
        h4 v; v[0] = v[1] = v[2] = v[3] = (_Float16)0.f;
        if (h >= 0 && h < H && w >= 0 && w < W) {
            const float* xp = x + ((size_t)b * C + 4 * q) * HW + h * W + w;
            v[0] = (_Float16)xp[0];
            v[1] = (_Float16)xp[HW];
            v[2] = (_Float16)xp[2 * HW];
            v[3] = (_Float16)xp[3 * HW];
        }
        xpad4[i] = v;
    }
    if (i < WDF_HALFS) {
        int m = i / 9216, r = i % 9216;
        int tap = r / 1024, l = (r >> 3) & 63, j = i & 7;
        int ks = (r >> 9) & 1;
        int o = m * 16 + (l & 15);
        int c = ks * 32 + ((l >> 4) << 3) + j;
        wdf[i] = (_Float16)w_dc[((size_t)o * C + c) * KT + tap];
    }
    if (i < WOF_HALFS) {
        int mf = i / 9216, r = i % 9216;
        int tap = r / 1024, l = (r >> 3) & 63, j = i & 7;
        int ks = (r >> 9) & 1;
        int oc = mf * 16 + (l & 15);
        int c = ks * 32 + ((l >> 4) << 3) + j;
        wof[i] = (oc < OFFC) ? (_Float16)w_off[((size_t)oc * C + c) * KT + tap]
                             : (_Float16)0.f;
    }
}

// ---------------------------------------------------------------------------
// Fused DCN, wave-autonomous + LDS-resident deform weights.
// Round-13: round-12's scheduling with the Phase-A pipeline ordering FIXED —
// consume-then-refill ((k+2)%3 == (k-1)%3, so refilling before the consume
// clobbers the set being read; that was round 12's absmax=2.57 bug; Phase B
// always had the correct order). wdf->LDS staging stays at Phase-A TAIL
// (vmcnt FIFO: staging at head forced every later gather-wait to drain it).
// ---------------------------------------------------------------------------
__global__ __launch_bounds__(256, 2) void fused_wave(
        const h4* __restrict__ xpad4, const _Float16* __restrict__ wdf,
        const _Float16* __restrict__ wof, const float* __restrict__ b_off,
        const float* __restrict__ b_dc, float* __restrict__ out) {
    const int lane = threadIdx.x & 63;
    const int wid = __builtin_amdgcn_readfirstlane(threadIdx.x >> 6);
    const int p = lane & 15, g = lane >> 4;
    const int bid = blockIdx.x;
    const int tile = (bid & 7) * 72 + (bid >> 3);   // XCD swizzle (576 = 8*72)
    const int wt = tile * 4 + wid;                  // wave-tile 0..2303
    const int flat0 = wt * 16;
    const int b_u = __builtin_amdgcn_readfirstlane(flat0 / HW);
    const int loc0 = flat0 - b_u * HW;
    const int h = loc0 / W;                         // uniform per wave (16|96)
    const int w = loc0 % W + p;                     // my pixel's column

    __shared__ _Float16 wlds[WDF_HALFS];            // 73728 B deform weights
    __shared__ float offt[4][2 * KT][16];           // 4608 B wave-private slabs

    const h4* xq = xpad4 + (size_t)b_u * NQ * HPWP;

    // ---------------- Phase A: offset conv ----------------
    {
        f32x4 a0 = {0.f,0.f,0.f,0.f}, a1 = {0.f,0.f,0.f,0.f};
        half8 bf[3][2];                             // [set = tap%3][ks]
        half8 wA[2][4];                             // [slot = tap&1][2ks*2of]
        const _Float16* wofb = wof + lane * 8;

        auto loadWA = [&](int slot, int k) {
            #pragma unroll
            for (int ks = 0; ks < 2; ++ks) {
                wA[slot][2 * ks]     = *(const half8*)(wofb + k * 1024 + ks * 512);
                wA[slot][2 * ks + 1] = *(const half8*)(wofb + 9216 + k * 1024 + ks * 512);
            }
        };
        auto issueA = [&](int s, int k) {
            const int cell = (h + k / 3 - 1 + PAD) * WP + (w + k % 3 - 1 + PAD);
            #pragma unroll
            for (int ks = 0; ks < 2; ++ks) {
                h4 q0 = xq[(size_t)(ks * 8 + 2 * g)     * HPWP + cell];
                h4 q1 = xq[(size_t)(ks * 8 + 2 * g + 1) * HPWP + cell];
                bf[s][ks] = __builtin_shufflevector(q0, q1, 0,1,2,3,4,5,6,7);
            }
        };
        auto mfmaA = [&](int s, int slot) {
            __builtin_amdgcn_s_setprio(1);
            #pragma unroll
            for (int ks = 0; ks < 2; ++ks) {
                a0 = __builtin_amdgcn_mfma_f32_16x16x32_f16(wA[slot][2*ks],   bf[s][ks], a0, 0, 0, 0);
                a1 = __builtin_amdgcn_mfma_f32_16x16x32_f16(wA[slot][2*ks+1], bf[s][ks], a1, 0, 0, 0);
            }
            __builtin_amdgcn_s_setprio(0);
        };

        loadWA(0, 0); loadWA(1, 1);                   // taps 0,1 weights
        issueA(0, 0); issueA(1, 1); issueA(2, 2);     // taps 0,1,2 gathers
        #pragma unroll
        for (int k = 1; k <= 8; ++k) {
            __builtin_amdgcn_sched_barrier(0);
            mfmaA((k - 1) % 3, (k - 1) & 1);          // consume tap k-1
            __builtin_amdgcn_sched_barrier(0);
            if (k <= 7) loadWA((k - 1) & 1, k + 1);   // tap k+1 -> freed slot
            if (k <= 6) issueA((k - 1) % 3, k + 2);   // tap k+2 -> freed set
        }

        // ---- stage wdf -> LDS at the TAIL of Phase A's VMEM stream ----
        // (72 segments of 1 KB; drains for free at the barrier below)
        #pragma unroll
        for (int s2 = 0; s2 < 18; ++s2) {
            const int seg = wid * 18 + s2;
            __builtin_amdgcn_global_load_lds(
                (const __attribute__((address_space(1))) unsigned int*)
                    (wdf + (size_t)seg * 512 + lane * 8),
                (__attribute__((address_space(3))) unsigned int*)
                    &wlds[seg * 512],
                16, 0, 0);
        }
        __builtin_amdgcn_sched_barrier(0);
        mfmaA(8 % 3, 8 & 1);                          // tap 8 (set 2, slot 0)

        #pragma unroll
        for (int r = 0; r < 4; ++r) {                 // oc 0..15
            const int oc = g * 4 + r;
            offt[wid][oc][p] = a0[r] + b_off[oc];
        }
        if (g == 0) {                                 // oc 16,17
            #pragma unroll
            for (int r = 0; r < 2; ++r)
                offt[wid][16 + r][p] = a1[r] + b_off[16 + r];
        }
    }
    __syncthreads();    // drains wdf staging (vmcnt 0) + publishes wlds

    // ---------------- Phase B: deformable conv ----------------
    {
        f32x4 acc[4] = {{0.f,0.f,0.f,0.f},{0.f,0.f,0.f,0.f},
                        {0.f,0.f,0.f,0.f},{0.f,0.f,0.f,0.f}};
        h4x2 rt[3][2][2], rb[3][2][2];                // [set][ks][q2]
        h4 Wc[3][4];                                  // [set][corner] splats
        const _Float16* wl = wlds + lane * 8;         // my fragment column

        auto issueB = [&](int s, int k) {
            const float dy = offt[wid][2 * k][p];
            const float dx = offt[wid][2 * k + 1][p];
            const float py = (float)(h + k / 3 - 1) + dy;
            const float px = (float)(w + k % 3 - 1) + dx;
            const float y0f = floorf(py), x0f = floorf(px);
            const float ly = py - y0f, lx = px - x0f;
            int y0 = (int)y0f, x0 = (int)x0f;
            y0 = min(max(y0, -PAD), H + PAD - 2);     // clamp lands in zero halo
            x0 = min(max(x0, -PAD), W + PAD - 2);
            const int base = (y0 + PAD) * WP + (x0 + PAD);
            const float a11 = ly * lx;
            const _Float16 f11 = (_Float16)a11;
            const _Float16 f10 = (_Float16)(ly - a11);
            const _Float16 f01 = (_Float16)(lx - a11);
            const _Float16 f00 = (_Float16)(1.f - ly - lx + a11);
            #pragma unroll
            for (int e = 0; e < 4; ++e) { Wc[s][0][e] = f00; Wc[s][1][e] = f01;
                                          Wc[s][2][e] = f10; Wc[s][3][e] = f11; }
            #pragma unroll
            for (int ks = 0; ks < 2; ++ks) {
                #pragma unroll
                for (int q2 = 0; q2 < 2; ++q2) {
                    const h4* qp = xq + (size_t)(ks * 8 + 2 * g + q2) * HPWP + base;
                    __builtin_memcpy(&rt[s][ks][q2], qp, 16);        // (y0, x0..x0+1)
                    __builtin_memcpy(&rb[s][ks][q2], qp + WP, 16);   // (y0+1, ...)
                }
            }
        };
        auto mfmaB = [&](int s, int k) {
            #pragma unroll
            for (int ks = 0; ks < 2; ++ks) {
                h4 s0 = rt[s][ks][0].a * Wc[s][0] + rt[s][ks][0].b * Wc[s][1]
                      + rb[s][ks][0].a * Wc[s][2] + rb[s][ks][0].b * Wc[s][3];
                h4 s1 = rt[s][ks][1].a * Wc[s][0] + rt[s][ks][1].b * Wc[s][1]
                      + rb[s][ks][1].a * Wc[s][2] + rb[s][ks][1].b * Wc[s][3];
                half8 bfr = __builtin_shufflevector(s0, s1, 0,1,2,3,4,5,6,7);
                __builtin_amdgcn_s_setprio(1);
                #pragma unroll
                for (int m = 0; m < 4; ++m) {
                    half8 wf = *(const half8*)(wl + m * 9216 + k * 1024 + ks * 512);
                    acc[m] = __builtin_amdgcn_mfma_f32_16x16x32_f16(wf, bfr,
                                                                    acc[m], 0, 0, 0);
                }
                __builtin_amdgcn_s_setprio(0);
            }
        };

        issueB(0, 0); issueB(1, 1); issueB(2, 2);     // 3-deep prologue
        #pragma unroll
        for (int k = 1; k <= 8; ++k) {
            __builtin_amdgcn_sched_barrier(0);
            mfmaB((k - 1) % 3, k - 1);                // consume tap k-1
            __builtin_amdgcn_sched_barrier(0);
            if (k <= 6) issueB((k - 1) % 3, k + 2);   // tap k+2 -> freed set
        }
        mfmaB(8 % 3, 8);                              // tap 8

        #pragma unroll
        for (int m = 0; m < 4; ++m) {
            #pragma unroll
            for (int r = 0; r < 4; ++r) {
                const int o = m * 16 + g * 4 + r;
                out[((size_t)b_u * C + o) * HW + loc0 + p] = acc[m][r] + b_dc[o];
            }
        }
    }
}

// ---------------------------------------------------------------------------
extern "C" void kernel_launch(void* const* d_in, const int* in_sizes, int n_in,
                              void* d_out, int out_size, void* d_ws, size_t ws_size,
                              hipStream_t stream) {
    const float* x     = (const float*)d_in[0];
    const float* w_off = (const float*)d_in[1];
    const float* b_off = (const float*)d_in[2];
    const float* w_dc  = (const float*)d_in[3];
    const float* b_dc  = (const float*)d_in[4];
    float* out = (float*)d_out;

    char* ws = (char*)d_ws;
    h4*        xpad4 = (h4*)ws;                            // 692224 * 8B = 5537792 B
    _Float16*  wdf   = (_Float16*)(ws + 5537792);          // 36864 h
    _Float16*  wof   = (_Float16*)(ws + 5537792 + 73728);  // 18432 h

    prep<<<B * NQ * HPWP / 256, 256, 0, stream>>>(x, w_off, w_dc, xpad4, wdf, wof);
    fused_wave<<<576, 256, 0, stream>>>(xpad4, wdf, wof, b_off, b_dc, out);
}

// Round 14
// 26.485 us; speedup vs baseline: 1.1658x; 1.1658x over previous
//
#include <hip/hip_runtime.h>
#include <math.h>

typedef _Float16 h4    __attribute__((ext_vector_type(4)));
typedef _Float16 half8 __attribute__((ext_vector_type(8)));
typedef float    f32x4 __attribute__((ext_vector_type(4)));

constexpr int B = 4, C = 64, H = 96, W = 96;
constexpr int NQ = C / 4;                   // 16 channel-quads
constexpr int KT = 9, OFFC = 18;
constexpr int HW = H * W;
constexpr int PAD = 4;                      // zero halo
constexpr int HP = H + 2 * PAD, WP = W + 2 * PAD;   // 104 x 104
constexpr int HPWP = HP * WP;
constexpr int WDF_HALFS = 4 * KT * 2 * 64 * 8;   // 36864  [m][tap][ks][lane][j]
constexpr int WOF_HALFS = 2 * KT * 2 * 64 * 8;   // 18432  [mf][tap][ks][lane][j]
constexpr int NWAVE = 9;                    // waves per block (2304/256 CUs = 9)

struct h4x2 { h4 a, b; };                   // 16B: two adjacent columns (x0, x0+1)

// ---------------------------------------------------------------------------
// Prep: quad-interleaved f16 zero-halo pad + MFMA A-frag weights
// (identical to rounds 10-13; layouts verified).
// ---------------------------------------------------------------------------
__global__ __launch_bounds__(256) void prep(
        const float* __restrict__ x, const float* __restrict__ w_off,
        const float* __restrict__ w_dc,
        h4* __restrict__ xpad4, _Float16* __restrict__ wdf,
        _Float16* __restrict__ wof) {
    const int i = blockIdx.x * 256 + threadIdx.x;   // covers B*NQ*HPWP exactly
    {
        int col = i % WP; int t = i / WP; int row = t % HP; int bq = t / HP;
        int b = bq / NQ, q = bq % NQ;
        int h = row - PAD, w = col - PAD;
        h4 v; v[0] = v[1] = v[2] = v[3] = (_Float16)0.f;
        if (h >= 0 && h < H && w >= 0 && w < W) {
            const float* xp = x + ((size_t)b * C + 4 * q) * HW + h * W + w;
            v[0] = (_Float16)xp[0];
            v[1] = (_Float16)xp[HW];
            v[2] = (_Float16)xp[2 * HW];
            v[3] = (_Float16)xp[3 * HW];
        }
        xpad4[i] = v;
    }
    if (i < WDF_HALFS) {
        int m = i / 9216, r = i % 9216;
        int tap = r / 1024, l = (r >> 3) & 63, j = i & 7;
        int ks = (r >> 9) & 1;
        int o = m * 16 + (l & 15);
        int c = ks * 32 + ((l >> 4) << 3) + j;
        wdf[i] = (_Float16)w_dc[((size_t)o * C + c) * KT + tap];
    }
    if (i < WOF_HALFS) {
        int mf = i / 9216, r = i % 9216;
        int tap = r / 1024, l = (r >> 3) & 63, j = i & 7;
        int ks = (r >> 9) & 1;
        int oc = mf * 16 + (l & 15);
        int c = ks * 32 + ((l >> 4) << 3) + j;
        wof[i] = (oc < OFFC) ? (_Float16)w_off[((size_t)oc * C + c) * KT + tap]
                             : (_Float16)0.f;
    }
}

// ---------------------------------------------------------------------------
// Fused DCN, wave-autonomous, LDS-resident deform weights.
// Round-14 grid: block = 9 waves x 16-pixel tiles = 144 px; grid = 256 blocks
// = EXACTLY 1/CU, 9 wave-tiles/CU (2304/256) — perfect balance, no straggler
// round (r10-13's 576-block grid left 64 blocks in a serial 3rd round).
// LDS 84 KB -> 1 block/CU by construction. 2-deep pipelines (r11-proven;
// 3-deep was neutral and the 576-thread flat-wg VGPR cap is 170).
// ---------------------------------------------------------------------------
__global__ __launch_bounds__(NWAVE * 64) void fused_wave(
        const h4* __restrict__ xpad4, const _Float16* __restrict__ wdf,
        const _Float16* __restrict__ wof, const float* __restrict__ b_off,
        const float* __restrict__ b_dc, float* __restrict__ out) {
    const int lane = threadIdx.x & 63;
    const int wid = __builtin_amdgcn_readfirstlane(threadIdx.x >> 6);  // 0..8
    const int p = lane & 15, g = lane >> 4;
    const int bid = blockIdx.x;
    const int tile = (bid & 7) * 32 + (bid >> 3);   // XCD swizzle (256 = 8*32)
    const int flat0 = tile * 144 + wid * 16;        // 144 | 9216: one batch/block
    const int b_u = __builtin_amdgcn_readfirstlane(flat0 / HW);
    const int loc0 = flat0 - b_u * HW;
    const int h = loc0 / W;                         // uniform per wave (16 | 96)
    const int w = loc0 % W + p;                     // my pixel's column

    __shared__ _Float16 wlds[WDF_HALFS];            // 73728 B deform weights
    __shared__ float offt[NWAVE][2 * KT][16];       // 10368 B wave-private slabs

    const h4* xq = xpad4 + (size_t)b_u * NQ * HPWP;

    // ---------------- Phase A: offset conv ----------------
    {
        f32x4 a0 = {0.f,0.f,0.f,0.f}, a1 = {0.f,0.f,0.f,0.f};
        half8 bf[2][2];                             // [set = tap&1][ks]
        half8 wA[2][4];                             // [slot = tap&1][2ks*2of]
        const _Float16* wofb = wof + lane * 8;

        auto loadWA = [&](int slot, int k) {
            #pragma unroll
            for (int ks = 0; ks < 2; ++ks) {
                wA[slot][2 * ks]     = *(const half8*)(wofb + k * 1024 + ks * 512);
                wA[slot][2 * ks + 1] = *(const half8*)(wofb + 9216 + k * 1024 + ks * 512);
            }
        };
        auto issueA = [&](int s, int k) {
            const int cell = (h + k / 3 - 1 + PAD) * WP + (w + k % 3 - 1 + PAD);
            #pragma unroll
            for (int ks = 0; ks < 2; ++ks) {
                h4 q0 = xq[(size_t)(ks * 8 + 2 * g)     * HPWP + cell];
                h4 q1 = xq[(size_t)(ks * 8 + 2 * g + 1) * HPWP + cell];
                bf[s][ks] = __builtin_shufflevector(q0, q1, 0,1,2,3,4,5,6,7);
            }
        };
        auto mfmaA = [&](int s, int slot) {
            __builtin_amdgcn_s_setprio(1);
            #pragma unroll
            for (int ks = 0; ks < 2; ++ks) {
                a0 = __builtin_amdgcn_mfma_f32_16x16x32_f16(wA[slot][2*ks],   bf[s][ks], a0, 0, 0, 0);
                a1 = __builtin_amdgcn_mfma_f32_16x16x32_f16(wA[slot][2*ks+1], bf[s][ks], a1, 0, 0, 0);
            }
            __builtin_amdgcn_s_setprio(0);
        };

        loadWA(0, 0); loadWA(1, 1);                 // taps 0,1 weights
        issueA(0, 0); issueA(1, 1);                 // taps 0,1 gathers
        #pragma unroll
        for (int k = 1; k <= 8; ++k) {
            __builtin_amdgcn_sched_barrier(0);
            mfmaA((k - 1) & 1, (k - 1) & 1);        // consume tap k-1
            __builtin_amdgcn_sched_barrier(0);
            if (k <= 7) {                           // tap k+1 -> freed set/slot
                loadWA((k - 1) & 1, k + 1);
                issueA((k - 1) & 1, k + 1);
            }
        }

        // ---- stage wdf -> LDS at the TAIL of Phase A's VMEM stream ----
        // (72 segments of 1 KB, 8 per wave; drains free at the barrier below)
        #pragma unroll
        for (int s2 = 0; s2 < 8; ++s2) {
            const int seg = wid * 8 + s2;
            __builtin_amdgcn_global_load_lds(
                (const __attribute__((address_space(1))) unsigned int*)
                    (wdf + (size_t)seg * 512 + lane * 8),
                (__attribute__((address_space(3))) unsigned int*)
                    &wlds[seg * 512],
                16, 0, 0);
        }
        __builtin_amdgcn_sched_barrier(0);
        mfmaA(8 & 1, 8 & 1);                        // tap 8

        #pragma unroll
        for (int r = 0; r < 4; ++r) {               // oc 0..15
            const int oc = g * 4 + r;
            offt[wid][oc][p] = a0[r] + b_off[oc];
        }
        if (g == 0) {                               // oc 16,17
            #pragma unroll
            for (int r = 0; r < 2; ++r)
                offt[wid][16 + r][p] = a1[r] + b_off[16 + r];
        }
    }
    __syncthreads();    // drains wdf staging (vmcnt 0) + publishes wlds

    // ---------------- Phase B: deformable conv ----------------
    {
        f32x4 acc[4] = {{0.f,0.f,0.f,0.f},{0.f,0.f,0.f,0.f},
                        {0.f,0.f,0.f,0.f},{0.f,0.f,0.f,0.f}};
        h4x2 rt[2][2][2], rb[2][2][2];              // [set][ks][q2]
        h4 Wc[2][4];                                // [set][corner] splats
        const _Float16* wl = wlds + lane * 8;       // my fragment column

        auto issueB = [&](int s, int k) {
            const float dy = offt[wid][2 * k][p];
            const float dx = offt[wid][2 * k + 1][p];
            const float py = (float)(h + k / 3 - 1) + dy;
            const float px = (float)(w + k % 3 - 1) + dx;
            const float y0f = floorf(py), x0f = floorf(px);
            const float ly = py - y0f, lx = px - x0f;
            int y0 = (int)y0f, x0 = (int)x0f;
            y0 = min(max(y0, -PAD), H + PAD - 2);   // clamp lands in zero halo
            x0 = min(max(x0, -PAD), W + PAD - 2);
            const int base = (y0 + PAD) * WP + (x0 + PAD);
            const float a11 = ly * lx;
            const _Float16 f11 = (_Float16)a11;
            const _Float16 f10 = (_Float16)(ly - a11);
            const _Float16 f01 = (_Float16)(lx - a11);
            const _Float16 f00 = (_Float16)(1.f - ly - lx + a11);
            #pragma unroll
            for (int e = 0; e < 4; ++e) { Wc[s][0][e] = f00; Wc[s][1][e] = f01;
                                          Wc[s][2][e] = f10; Wc[s][3][e] = f11; }
            #pragma unroll
            for (int ks = 0; ks < 2; ++ks) {
                #pragma unroll
                for (int q2 = 0; q2 < 2; ++q2) {
                    const h4* qp = xq + (size_t)(ks * 8 + 2 * g + q2) * HPWP + base;
                    __builtin_memcpy(&rt[s][ks][q2], qp, 16);        // (y0, x0..x0+1)
                    __builtin_memcpy(&rb[s][ks][q2], qp + WP, 16);   // (y0+1, ...)
                }
            }
        };
        auto mfmaB = [&](int s, int k) {
            #pragma unroll
            for (int ks = 0; ks < 2; ++ks) {
                h4 s0 = rt[s][ks][0].a * Wc[s][0] + rt[s][ks][0].b * Wc[s][1]
                      + rb[s][ks][0].a * Wc[s][2] + rb[s][ks][0].b * Wc[s][3];
                h4 s1 = rt[s][ks][1].a * Wc[s][0] + rt[s][ks][1].b * Wc[s][1]
                      + rb[s][ks][1].a * Wc[s][2] + rb[s][ks][1].b * Wc[s][3];
                half8 bfr = __builtin_shufflevector(s0, s1, 0,1,2,3,4,5,6,7);
                __builtin_amdgcn_s_setprio(1);
                #pragma unroll
                for (int m = 0; m < 4; ++m) {
                    half8 wf = *(const half8*)(wl + m * 9216 + k * 1024 + ks * 512);
                    acc[m] = __builtin_amdgcn_mfma_f32_16x16x32_f16(wf, bfr,
                                                                    acc[m], 0, 0, 0);
                }
                __builtin_amdgcn_s_setprio(0);
            }
        };

        issueB(0, 0); issueB(1, 1);                 // 2-deep prologue
        #pragma unroll
        for (int k = 1; k <= 8; ++k) {
            __builtin_amdgcn_sched_barrier(0);
            mfmaB((k - 1) & 1, k - 1);              // consume tap k-1
            __builtin_amdgcn_sched_barrier(0);
            if (k <= 7) issueB((k - 1) & 1, k + 1); // tap k+1 -> freed set
        }
        mfmaB(8 & 1, 8);                            // tap 8

        #pragma unroll
        for (int m = 0; m < 4; ++m) {
            #pragma unroll
            for (int r = 0; r < 4; ++r) {
                const int o = m * 16 + g * 4 + r;
                out[((size_t)b_u * C + o) * HW + loc0 + p] = acc[m][r] + b_dc[o];
            }
        }
    }
}

// ---------------------------------------------------------------------------
extern "C" void kernel_launch(void* const* d_in, const int* in_sizes, int n_in,
                              void* d_out, int out_size, void* d_ws, size_t ws_size,
                              hipStream_t stream) {
    const float* x     = (const float*)d_in[0];
    const float* w_off = (const float*)d_in[1];
    const float* b_off = (const float*)d_in[2];
    const float* w_dc  = (const float*)d_in[3];
    const float* b_dc  = (const float*)d_in[4];
    float* out = (float*)d_out;

    char* ws = (char*)d_ws;
    h4*        xpad4 = (h4*)ws;                            // 692224 * 8B = 5537792 B
    _Float16*  wdf   = (_Float16*)(ws + 5537792);          // 36864 h
    _Float16*  wof   = (_Float16*)(ws + 5537792 + 73728);  // 18432 h

    prep<<<B * NQ * HPWP / 256, 256, 0, stream>>>(x, w_off, w_dc, xpad4, wdf, wof);
    fused_wave<<<256, NWAVE * 64, 0, stream>>>(xpad4, wdf, wof, b_off, b_dc, out);
}